// Round 12
// baseline (737.032 us; speedup 1.0000x reference)
//
#include <hip/hip_runtime.h>

#define N_NODES 100000
#define N_EDGES 1600000
#define D 128

typedef __attribute__((ext_vector_type(8))) short bf16x8;
typedef __attribute__((ext_vector_type(4))) float f32x4;
typedef __attribute__((ext_vector_type(2))) float f32x2;

// ---- bucketing geometry ----
#define BSHIFT 8
#define BNODES 256                       // nodes per bucket
#define NBUCK 391                        // ceil(100000/256)
#define BCAP 8192                        // pairs capacity per bucket (mean 4092)
#define EPB 4096                         // edges per bin block
#define NDEG 64                          // degree-sort bins (deg clamped to 63)

// ---- scratch in the module's device data segment ----
// All cursor/histogram arrays are .bss-zero at load and re-zeroed by sag_fused
// (after they are dead) -> every kernel_launch sees zeros (replay-deterministic).
__device__ int g_bcur[NBUCK];
__device__ int g_dhist[NDEG];
__device__ int g_dbase[NDEG];
__device__ int g_perm[N_NODES];          // nodes sorted by degree
__device__ int g_rowptr[N_NODES + 1];
__device__ int g_csr[N_EDGES];
__device__ unsigned g_pairs[(size_t)NBUCK * BCAP];   // (loc<<24)|src
__device__ unsigned short g_xh[N_NODES * D];  // x in bf16
__device__ uint2 g_xq[N_NODES * 16];          // x in fp8 e4m3 (gather stream), row = 128B
__device__ unsigned short g_wh[256 * D];      // [Ws;Wn] transposed, LINEAR [n][k]

__device__ inline unsigned rne1(float f) {       // f32 -> bf16 bits, round-nearest-even
    unsigned b = __float_as_uint(f);
    return (b + 0x7FFFu + ((b >> 16) & 1u)) >> 16;
}
__device__ inline unsigned pack2(float a, float b) { return rne1(a) | (rne1(b) << 16); }
__device__ inline float bflo(unsigned u) { return __uint_as_float(u << 16); }
__device__ inline float bfhi(unsigned u) { return __uint_as_float(u & 0xFFFF0000u); }

// K1: blocks [0,6250): x -> g_xh (bf16) + g_xq (fp8)
//     blocks [6250,6378): W -> g_wh (LINEAR [n][k])
//     blocks [6378,6769): bin edges into per-bucket segments
__global__ __launch_bounds__(256) void prep_bin(const float* __restrict__ x,
                                                const float* __restrict__ Ws,
                                                const float* __restrict__ Wn,
                                                const int* __restrict__ ei)
{
    const int b = blockIdx.x;
    if (b < 6250) {
        const int i = b * 256 + threadIdx.x;       // uint4 chunk index (1.6M)
        const float4 f0 = reinterpret_cast<const float4*>(x)[i * 2 + 0];
        const float4 f1 = reinterpret_cast<const float4*>(x)[i * 2 + 1];
        uint4 o;
        o.x = pack2(f0.x, f0.y);
        o.y = pack2(f0.z, f0.w);
        o.z = pack2(f1.x, f1.y);
        o.w = pack2(f1.z, f1.w);
        reinterpret_cast<uint4*>(g_xh)[i] = o;
        int lo = __builtin_amdgcn_cvt_pk_fp8_f32(f0.x, f0.y, 0, false);
        lo = __builtin_amdgcn_cvt_pk_fp8_f32(f0.z, f0.w, lo, true);
        int hi = __builtin_amdgcn_cvt_pk_fp8_f32(f1.x, f1.y, 0, false);
        hi = __builtin_amdgcn_cvt_pk_fp8_f32(f1.z, f1.w, hi, true);
        g_xq[i] = make_uint2((unsigned)lo, (unsigned)hi);
    } else if (b < 6378) {
        const int tid = (b - 6250) * 256 + threadIdx.x;   // 32768
        const int k = tid >> 7, n = tid & 127;
        const float v = (k < 128) ? Ws[k * 128 + n] : Wn[(k - 128) * 128 + n];
        g_wh[n * 256 + k] = (unsigned short)rne1(v);
    } else {
        __shared__ int cnt[NBUCK];
        __shared__ int cur[NBUCK];
        const int t = threadIdx.x;
        const int e0 = (b - 6378) * EPB;

        for (int k = t; k < NBUCK; k += 256) cnt[k] = 0;
        __syncthreads();

        int dstv[16], srcv[16];
        #pragma unroll
        for (int i = 0; i < 16; ++i) {
            const int e = e0 + i * 256 + t;
            if (e < N_EDGES) {
                dstv[i] = ei[N_EDGES + e];
                srcv[i] = ei[e];
                atomicAdd(&cnt[dstv[i] >> BSHIFT], 1);
            } else {
                dstv[i] = -1;
            }
        }
        __syncthreads();

        for (int k = t; k < NBUCK; k += 256) {
            const int c = cnt[k];
            cur[k] = (c > 0) ? atomicAdd(&g_bcur[k], c) : 0;
        }
        __syncthreads();

        #pragma unroll
        for (int i = 0; i < 16; ++i) {
            if (dstv[i] >= 0) {
                const int bk = dstv[i] >> BSHIFT;
                const int r = atomicAdd(&cur[bk], 1);
                g_pairs[(size_t)bk * BCAP + r] =
                    ((unsigned)(dstv[i] & (BNODES - 1)) << 24) | (unsigned)srcv[i];
            }
        }
    }
}

// K2: one block per bucket -> g_rowptr + g_csr + degree histogram.
__global__ __launch_bounds__(256) void bucket_build()
{
    __shared__ int red[256];
    __shared__ int lcnt[BNODES];
    __shared__ int lsum[BNODES];
    const int t = threadIdx.x;
    const int b = blockIdx.x;
    const int nE = g_bcur[b];
    const unsigned* __restrict__ seg = &g_pairs[(size_t)b * BCAP];

    int partial = 0;
    for (int i = t; i < b; i += 256) partial += g_bcur[i];
    red[t] = partial;
    lcnt[t] = 0;
    __syncthreads();
    for (int off = 128; off > 0; off >>= 1) {
        if (t < off) red[t] += red[t + off];
        __syncthreads();
    }
    const int base_edge = red[0];

    for (int i = t; i < nE; i += 256)
        atomicAdd(&lcnt[seg[i] >> 24], 1);
    __syncthreads();
    lsum[t] = lcnt[t];
    __syncthreads();
    for (int off = 1; off < 256; off <<= 1) {
        int add = (t >= off) ? lsum[t - off] : 0;
        __syncthreads();
        lsum[t] += add;
        __syncthreads();
    }
    const int excl = lsum[t] - lcnt[t];
    const int node = (b << BSHIFT) + t;
    if (node <= N_NODES) g_rowptr[node] = base_edge + excl;
    if (node < N_NODES) atomicAdd(&g_dhist[min(lcnt[t], NDEG - 1)], 1);
    __syncthreads();
    lsum[t] = base_edge + excl;     // reuse as running cursor
    __syncthreads();
    for (int i = t; i < nE; i += 256) {
        const unsigned p = seg[i];
        const int pos = atomicAdd(&lsum[p >> 24], 1);
        g_csr[pos] = (int)(p & 0xFFFFFFu);
    }
}

// K3: exclusive scan of the 64-bin degree histogram (trivial).
__global__ __launch_bounds__(64) void scan64()
{
    if (threadIdx.x == 0 && blockIdx.x == 0) {
        int run = 0;
        for (int i = 0; i < NDEG; ++i) { g_dbase[i] = run; run += g_dhist[i]; }
    }
}

// K4: counting-sort placement: perm groups nodes of equal degree.
__global__ __launch_bounds__(256) void place()
{
    const int n = blockIdx.x * 256 + threadIdx.x;
    if (n < N_NODES) {
        const int deg = min(g_rowptr[n + 1] - g_rowptr[n], NDEG - 1);
        const int pos = atomicAdd(&g_dbase[deg], 1);
        g_perm[pos] = n;
    }
}

// K5: fused gather + MFMA. 6250 blocks x 1024 threads (16 waves).
// Wave w gathers node g_perm[block*16+w] (equal-degree group -> max ~= mean,
// no barrier-coupling loss). a-row + x-row land in an 8KB swizzled LDS tile;
// waves 0-7 MFMA out[16 nodes] = [xh | a] @ [Ws;Wn] + bias (B from linear
// g_wh, L2-resident). Out rows scattered via lNid.
__global__ __launch_bounds__(1024) void sag_fused(
    const float* __restrict__ bias,
    float* __restrict__ out)
{
    __shared__ unsigned short lA[16 * 256];   // row w = [xh(128) | a(128)], swizzled 16B chunks
    __shared__ int lNid[16];

    const int t = threadIdx.x;
    if (blockIdx.x == 0) {                    // dead scratch -> reset for next call
        if (t < NBUCK) g_bcur[t] = 0;
        if (t >= 512 && t < 512 + NDEG) { g_dhist[t - 512] = 0; g_dbase[t - 512] = 0; }
    }

    const int w = t >> 6, l = t & 63;
    const int q = (l >> 4) & 3, c = l & 15;
    const int node = g_perm[blockIdx.x * 16 + w];
    if (l == 0) lNid[w] = node;

    // ---------------- gather phase (R10-proven inner loop) ----------------
    const int beg = g_rowptr[node];
    const int end = g_rowptr[node + 1];
    const int deg = end - beg;

    float acc[8];
    #pragma unroll
    for (int i = 0; i < 8; ++i) acc[i] = 0.f;

    #define ACC8(v) do {                                                  \
        f32x2 p0 = __builtin_amdgcn_cvt_pk_f32_fp8((v).x, false);         \
        f32x2 p1 = __builtin_amdgcn_cvt_pk_f32_fp8((v).x, true);          \
        f32x2 p2 = __builtin_amdgcn_cvt_pk_f32_fp8((v).y, false);         \
        f32x2 p3 = __builtin_amdgcn_cvt_pk_f32_fp8((v).y, true);          \
        acc[0] += p0.x; acc[1] += p0.y; acc[2] += p1.x; acc[3] += p1.y;   \
        acc[4] += p2.x; acc[5] += p2.y; acc[6] += p3.x; acc[7] += p3.y;   \
    } while (0)

    int base = beg;
    for (; base + 16 <= end; base += 16) {
        const int s0 = g_csr[base + 0 + q];
        const int s1 = g_csr[base + 4 + q];
        const int s2 = g_csr[base + 8 + q];
        const int s3 = g_csr[base + 12 + q];
        const uint2 v0 = g_xq[s0 * 16 + c];
        const uint2 v1 = g_xq[s1 * 16 + c];
        const uint2 v2 = g_xq[s2 * 16 + c];
        const uint2 v3 = g_xq[s3 * 16 + c];
        ACC8(v0); ACC8(v1); ACC8(v2); ACC8(v3);
    }
    for (; base < end; base += 4) {
        if (base + q < end) {
            const int s = g_csr[base + q];
            const uint2 v = g_xq[s * 16 + c];
            ACC8(v);
        }
    }
    #undef ACC8

    #pragma unroll
    for (int i = 0; i < 8; ++i) {
        acc[i] += __shfl_xor(acc[i], 16, 64);
        acc[i] += __shfl_xor(acc[i], 32, 64);
    }

    if (q == 0) {
        const uint4 xv = reinterpret_cast<const uint4*>(g_xh)[node * 16 + c];
        uint4 res = make_uint4(0u, 0u, 0u, 0u);
        if (deg > 0) {
            const float inv = 1.f / (float)deg;
            float r0 = acc[0] * inv - bflo(xv.x), r1 = acc[1] * inv - bfhi(xv.x);
            float r2 = acc[2] * inv - bflo(xv.y), r3 = acc[3] * inv - bfhi(xv.y);
            float r4 = acc[4] * inv - bflo(xv.z), r5 = acc[5] * inv - bfhi(xv.z);
            float r6 = acc[6] * inv - bflo(xv.w), r7 = acc[7] * inv - bfhi(xv.w);
            res.x = pack2(r0, r1); res.y = pack2(r2, r3);
            res.z = pack2(r4, r5); res.w = pack2(r6, r7);
        }
        const int cs = c ^ (w & 7);            // swizzled 16B-chunk index
        *reinterpret_cast<uint4*>(&lA[w * 256 + (cs << 3)]) = xv;          // chunk cs
        *reinterpret_cast<uint4*>(&lA[w * 256 + ((16 + cs) << 3)]) = res;  // chunk 16+cs
    }
    __syncthreads();

    // ---------------- MFMA phase: waves 0-7, wave w -> cols [16w,16w+16) ----------------
    if (w >= 8) return;
    const int lg = l >> 4, l15 = l & 15;

    bf16x8 a[8];
    #pragma unroll
    for (int kt = 0; kt < 8; ++kt) {
        const int ch = (kt * 4 + lg) ^ (l15 & 7);   // swizzle on low 3 bits
        a[kt] = *reinterpret_cast<const bf16x8*>(&lA[l15 * 256 + (ch << 3)]);
    }

    const bf16x8* __restrict__ wp = reinterpret_cast<const bf16x8*>(g_wh);  // row n = 32 chunks
    const int n = w * 16 + l15;
    bf16x8 bfr[8];
    #pragma unroll
    for (int kt = 0; kt < 8; ++kt) bfr[kt] = wp[n * 32 + kt * 4 + lg];

    f32x4 accd = {0.f, 0.f, 0.f, 0.f};
    #pragma unroll
    for (int kt = 0; kt < 8; ++kt)
        accd = __builtin_amdgcn_mfma_f32_16x16x32_bf16(a[kt], bfr[kt], accd, 0, 0, 0);

    const float bv = bias[n];
    #pragma unroll
    for (int i = 0; i < 4; ++i)
        out[lNid[lg * 4 + i] * D + n] = accd[i] + bv;   // D: row=4*(l>>4)+i, col=l&15
}

extern "C" void kernel_launch(void* const* d_in, const int* in_sizes, int n_in,
                              void* d_out, int out_size, void* d_ws, size_t ws_size,
                              hipStream_t stream) {
    const float* x     = (const float*)d_in[0];
    const int* ei      = (const int*)d_in[1];
    const float* Ws    = (const float*)d_in[2];
    const float* Wn    = (const float*)d_in[3];
    const float* bias  = (const float*)d_in[4];
    float* out = (float*)d_out;

    prep_bin<<<6769, 256, 0, stream>>>(x, Ws, Wn, ei);      // 6250 cvt + 128 W + 391 bin
    bucket_build<<<NBUCK, 256, 0, stream>>>();              // 391 blocks
    scan64<<<1, 64, 0, stream>>>();
    place<<<(N_NODES + 255) / 256, 256, 0, stream>>>();     // 391 blocks
    sag_fused<<<N_NODES / 16, 1024, 0, stream>>>(bias, out); // 6250 blocks x 16 waves
}

// Round 13
// 177.013 us; speedup vs baseline: 4.1637x; 4.1637x over previous
//
#include <hip/hip_runtime.h>

#define N_NODES 100000
#define N_EDGES 1600000
#define D 128

typedef __attribute__((ext_vector_type(8))) short bf16x8;
typedef __attribute__((ext_vector_type(4))) float f32x4;
typedef __attribute__((ext_vector_type(2))) float f32x2;

// ---- bucketing geometry ----
#define BSHIFT 8
#define BNODES 256                       // nodes per bucket
#define NBUCK 391                        // ceil(100000/256)
#define BCAP 8192                        // pairs capacity per bucket (mean 4092)
#define EPB 4096                         // edges per bin block
#define NDEG 64                          // degree clamp for in-bucket sort

// ---- scratch in the module's device data segment ----
// g_bcur: .bss-zero at load; re-zeroed by sag_fused (after dead) -> every
// kernel_launch sees zeros (replay-deterministic).
__device__ int g_bcur[NBUCK];
__device__ int g_perm[N_NODES];          // degree-sorted within each 256-node bucket
__device__ int g_rowptr[N_NODES + 1];
__device__ int g_csr[N_EDGES];
__device__ unsigned g_pairs[(size_t)NBUCK * BCAP];   // (loc<<24)|src
__device__ unsigned short g_xh[N_NODES * D];  // x in bf16
__device__ uint2 g_xq[N_NODES * 16];          // x in fp8 e4m3 (gather stream), row = 128B
__device__ unsigned short g_wh[256 * D];      // [Ws;Wn] transposed, LINEAR [n][k]

__device__ inline unsigned rne1(float f) {       // f32 -> bf16 bits, round-nearest-even
    unsigned b = __float_as_uint(f);
    return (b + 0x7FFFu + ((b >> 16) & 1u)) >> 16;
}
__device__ inline unsigned pack2(float a, float b) { return rne1(a) | (rne1(b) << 16); }
__device__ inline float bflo(unsigned u) { return __uint_as_float(u << 16); }
__device__ inline float bfhi(unsigned u) { return __uint_as_float(u & 0xFFFF0000u); }

// K1: blocks [0,6250): x -> g_xh (bf16) + g_xq (fp8)
//     blocks [6250,6378): W -> g_wh (LINEAR [n][k])
//     blocks [6378,6769): bin edges into per-bucket segments
__global__ __launch_bounds__(256) void prep_bin(const float* __restrict__ x,
                                                const float* __restrict__ Ws,
                                                const float* __restrict__ Wn,
                                                const int* __restrict__ ei)
{
    const int b = blockIdx.x;
    if (b < 6250) {
        const int i = b * 256 + threadIdx.x;       // uint4 chunk index (1.6M)
        const float4 f0 = reinterpret_cast<const float4*>(x)[i * 2 + 0];
        const float4 f1 = reinterpret_cast<const float4*>(x)[i * 2 + 1];
        uint4 o;
        o.x = pack2(f0.x, f0.y);
        o.y = pack2(f0.z, f0.w);
        o.z = pack2(f1.x, f1.y);
        o.w = pack2(f1.z, f1.w);
        reinterpret_cast<uint4*>(g_xh)[i] = o;
        int lo = __builtin_amdgcn_cvt_pk_fp8_f32(f0.x, f0.y, 0, false);
        lo = __builtin_amdgcn_cvt_pk_fp8_f32(f0.z, f0.w, lo, true);
        int hi = __builtin_amdgcn_cvt_pk_fp8_f32(f1.x, f1.y, 0, false);
        hi = __builtin_amdgcn_cvt_pk_fp8_f32(f1.z, f1.w, hi, true);
        g_xq[i] = make_uint2((unsigned)lo, (unsigned)hi);
    } else if (b < 6378) {
        const int tid = (b - 6250) * 256 + threadIdx.x;   // 32768
        const int k = tid >> 7, n = tid & 127;
        const float v = (k < 128) ? Ws[k * 128 + n] : Wn[(k - 128) * 128 + n];
        g_wh[n * 256 + k] = (unsigned short)rne1(v);
    } else {
        __shared__ int cnt[NBUCK];
        __shared__ int cur[NBUCK];
        const int t = threadIdx.x;
        const int e0 = (b - 6378) * EPB;

        for (int k = t; k < NBUCK; k += 256) cnt[k] = 0;
        __syncthreads();

        int dstv[16], srcv[16];
        #pragma unroll
        for (int i = 0; i < 16; ++i) {
            const int e = e0 + i * 256 + t;
            if (e < N_EDGES) {
                dstv[i] = ei[N_EDGES + e];
                srcv[i] = ei[e];
                atomicAdd(&cnt[dstv[i] >> BSHIFT], 1);
            } else {
                dstv[i] = -1;
            }
        }
        __syncthreads();

        for (int k = t; k < NBUCK; k += 256) {
            const int c = cnt[k];
            cur[k] = (c > 0) ? atomicAdd(&g_bcur[k], c) : 0;
        }
        __syncthreads();

        #pragma unroll
        for (int i = 0; i < 16; ++i) {
            if (dstv[i] >= 0) {
                const int bk = dstv[i] >> BSHIFT;
                const int r = atomicAdd(&cur[bk], 1);
                g_pairs[(size_t)bk * BCAP + r] =
                    ((unsigned)(dstv[i] & (BNODES - 1)) << 24) | (unsigned)srcv[i];
            }
        }
    }
}

// K2: one block per bucket -> g_rowptr + g_csr + in-bucket degree sort
// (LDS counting sort, NO global atomics -> no contention).
__global__ __launch_bounds__(256) void bucket_build()
{
    __shared__ int red[256];
    __shared__ int lcnt[BNODES];
    __shared__ int lsum[BNODES];
    __shared__ int h64[NDEG];
    __shared__ int hs64[NDEG];
    const int t = threadIdx.x;
    const int b = blockIdx.x;
    const int nE = g_bcur[b];
    const unsigned* __restrict__ seg = &g_pairs[(size_t)b * BCAP];

    int partial = 0;
    for (int i = t; i < b; i += 256) partial += g_bcur[i];
    red[t] = partial;
    lcnt[t] = 0;
    __syncthreads();
    for (int off = 128; off > 0; off >>= 1) {
        if (t < off) red[t] += red[t + off];
        __syncthreads();
    }
    const int base_edge = red[0];

    for (int i = t; i < nE; i += 256)
        atomicAdd(&lcnt[seg[i] >> 24], 1);
    __syncthreads();
    lsum[t] = lcnt[t];
    __syncthreads();
    for (int off = 1; off < 256; off <<= 1) {
        int add = (t >= off) ? lsum[t - off] : 0;
        __syncthreads();
        lsum[t] += add;
        __syncthreads();
    }
    const int excl = lsum[t] - lcnt[t];
    const int node = (b << BSHIFT) + t;
    if (node <= N_NODES) g_rowptr[node] = base_edge + excl;
    __syncthreads();
    lsum[t] = base_edge + excl;     // reuse as running cursor
    __syncthreads();
    for (int i = t; i < nE; i += 256) {
        const unsigned p = seg[i];
        const int pos = atomicAdd(&lsum[p >> 24], 1);
        g_csr[pos] = (int)(p & 0xFFFFFFu);
    }

    // ---- in-bucket counting sort by degree -> g_perm (all in LDS) ----
    const int nN = min(N_NODES - (b << BSHIFT), BNODES);   // 256 (160 for last bucket)
    const int mydeg = min(lcnt[t], NDEG - 1);
    if (t < NDEG) h64[t] = 0;
    __syncthreads();
    if (t < nN) atomicAdd(&h64[mydeg], 1);                 // LDS atomics: cheap
    __syncthreads();
    if (t < NDEG) hs64[t] = h64[t];
    __syncthreads();
    for (int off = 1; off < NDEG; off <<= 1) {
        int add = (t < NDEG && t >= off) ? hs64[t - off] : 0;
        __syncthreads();
        if (t < NDEG) hs64[t] += add;
        __syncthreads();
    }
    if (t < NDEG) h64[t] = hs64[t] - h64[t];               // exclusive base -> cursor
    __syncthreads();
    if (t < nN) {
        const int r = atomicAdd(&h64[mydeg], 1);           // LDS cursor
        g_perm[(b << BSHIFT) + r] = node;
    }
}

// K3: fused gather + MFMA. 6250 blocks x 1024 threads (16 waves).
// Wave w gathers node g_perm[block*16+w]; in-bucket degree sort makes the 16
// degrees near-equal -> barrier max ~= mean (fixes R11's coupling loss).
// a-row + x-row land in an 8KB swizzled LDS tile; waves 0-7 MFMA
// out[16 nodes] = [xh | a] @ [Ws;Wn] + bias (B from linear g_wh, L2-resident).
__global__ __launch_bounds__(1024) void sag_fused(
    const float* __restrict__ bias,
    float* __restrict__ out)
{
    __shared__ unsigned short lA[16 * 256];   // row w = [xh(128) | a(128)], swizzled 16B chunks
    __shared__ int lNid[16];

    const int t = threadIdx.x;
    if (blockIdx.x == 0 && t < NBUCK) g_bcur[t] = 0;   // dead after K2; reset for next call

    const int w = t >> 6, l = t & 63;
    const int q = (l >> 4) & 3, c = l & 15;
    const int node = g_perm[blockIdx.x * 16 + w];
    if (l == 0) lNid[w] = node;

    // ---------------- gather phase (R10-proven inner loop) ----------------
    const int beg = g_rowptr[node];
    const int end = g_rowptr[node + 1];
    const int deg = end - beg;

    float acc[8];
    #pragma unroll
    for (int i = 0; i < 8; ++i) acc[i] = 0.f;

    #define ACC8(v) do {                                                  \
        f32x2 p0 = __builtin_amdgcn_cvt_pk_f32_fp8((v).x, false);         \
        f32x2 p1 = __builtin_amdgcn_cvt_pk_f32_fp8((v).x, true);          \
        f32x2 p2 = __builtin_amdgcn_cvt_pk_f32_fp8((v).y, false);         \
        f32x2 p3 = __builtin_amdgcn_cvt_pk_f32_fp8((v).y, true);          \
        acc[0] += p0.x; acc[1] += p0.y; acc[2] += p1.x; acc[3] += p1.y;   \
        acc[4] += p2.x; acc[5] += p2.y; acc[6] += p3.x; acc[7] += p3.y;   \
    } while (0)

    int base = beg;
    for (; base + 16 <= end; base += 16) {
        const int s0 = g_csr[base + 0 + q];
        const int s1 = g_csr[base + 4 + q];
        const int s2 = g_csr[base + 8 + q];
        const int s3 = g_csr[base + 12 + q];
        const uint2 v0 = g_xq[s0 * 16 + c];
        const uint2 v1 = g_xq[s1 * 16 + c];
        const uint2 v2 = g_xq[s2 * 16 + c];
        const uint2 v3 = g_xq[s3 * 16 + c];
        ACC8(v0); ACC8(v1); ACC8(v2); ACC8(v3);
    }
    for (; base < end; base += 4) {
        if (base + q < end) {
            const int s = g_csr[base + q];
            const uint2 v = g_xq[s * 16 + c];
            ACC8(v);
        }
    }
    #undef ACC8

    #pragma unroll
    for (int i = 0; i < 8; ++i) {
        acc[i] += __shfl_xor(acc[i], 16, 64);
        acc[i] += __shfl_xor(acc[i], 32, 64);
    }

    if (q == 0) {
        const uint4 xv = reinterpret_cast<const uint4*>(g_xh)[node * 16 + c];
        uint4 res = make_uint4(0u, 0u, 0u, 0u);
        if (deg > 0) {
            const float inv = 1.f / (float)deg;
            float r0 = acc[0] * inv - bflo(xv.x), r1 = acc[1] * inv - bfhi(xv.x);
            float r2 = acc[2] * inv - bflo(xv.y), r3 = acc[3] * inv - bfhi(xv.y);
            float r4 = acc[4] * inv - bflo(xv.z), r5 = acc[5] * inv - bfhi(xv.z);
            float r6 = acc[6] * inv - bflo(xv.w), r7 = acc[7] * inv - bfhi(xv.w);
            res.x = pack2(r0, r1); res.y = pack2(r2, r3);
            res.z = pack2(r4, r5); res.w = pack2(r6, r7);
        }
        const int cs = c ^ (w & 7);            // swizzled 16B-chunk index
        *reinterpret_cast<uint4*>(&lA[w * 256 + (cs << 3)]) = xv;          // chunk cs
        *reinterpret_cast<uint4*>(&lA[w * 256 + ((16 + cs) << 3)]) = res;  // chunk 16+cs
    }
    __syncthreads();

    // ---------------- MFMA phase: waves 0-7, wave w -> cols [16w,16w+16) ----------------
    if (w >= 8) return;
    const int lg = l >> 4, l15 = l & 15;

    bf16x8 a[8];
    #pragma unroll
    for (int kt = 0; kt < 8; ++kt) {
        const int ch = (kt * 4 + lg) ^ (l15 & 7);   // swizzle on low 3 bits
        a[kt] = *reinterpret_cast<const bf16x8*>(&lA[l15 * 256 + (ch << 3)]);
    }

    const bf16x8* __restrict__ wp = reinterpret_cast<const bf16x8*>(g_wh);  // row n = 32 chunks
    const int n = w * 16 + l15;
    bf16x8 bfr[8];
    #pragma unroll
    for (int kt = 0; kt < 8; ++kt) bfr[kt] = wp[n * 32 + kt * 4 + lg];

    f32x4 accd = {0.f, 0.f, 0.f, 0.f};
    #pragma unroll
    for (int kt = 0; kt < 8; ++kt)
        accd = __builtin_amdgcn_mfma_f32_16x16x32_bf16(a[kt], bfr[kt], accd, 0, 0, 0);

    const float bv = bias[n];
    #pragma unroll
    for (int i = 0; i < 4; ++i)
        out[lNid[lg * 4 + i] * D + n] = accd[i] + bv;   // D: row=4*(l>>4)+i, col=l&15
}

extern "C" void kernel_launch(void* const* d_in, const int* in_sizes, int n_in,
                              void* d_out, int out_size, void* d_ws, size_t ws_size,
                              hipStream_t stream) {
    const float* x     = (const float*)d_in[0];
    const int* ei      = (const int*)d_in[1];
    const float* Ws    = (const float*)d_in[2];
    const float* Wn    = (const float*)d_in[3];
    const float* bias  = (const float*)d_in[4];
    float* out = (float*)d_out;

    prep_bin<<<6769, 256, 0, stream>>>(x, Ws, Wn, ei);      // 6250 cvt + 128 W + 391 bin
    bucket_build<<<NBUCK, 256, 0, stream>>>();              // 391 blocks
    sag_fused<<<N_NODES / 16, 1024, 0, stream>>>(bias, out); // 6250 blocks x 16 waves
}

// Round 14
// 141.628 us; speedup vs baseline: 5.2040x; 1.2498x over previous
//
#include <hip/hip_runtime.h>

#define N_NODES 100000
#define N_EDGES 1600000
#define D 128

typedef __attribute__((ext_vector_type(8))) short bf16x8;
typedef __attribute__((ext_vector_type(4))) float f32x4;
typedef __attribute__((ext_vector_type(2))) float f32x2;

// ---- bucketing geometry ----
#define BSHIFT 8
#define BNODES 256                       // nodes per bucket
#define NBUCK 391                        // ceil(100000/256)
#define BCAP 8192                        // pairs capacity per bucket (mean 4092)
#define EPB 4096                         // edges per bin block

// ---- scratch in the module's device data segment ----
// g_bcur: .bss-zero at load; re-zeroed by sag_gemm_mfma (last kernel, after
// dead) -> every kernel_launch sees zeros (replay-deterministic).
__device__ int g_bcur[NBUCK];
__device__ int g_rowptr[N_NODES + 1];
__device__ int g_csr[N_EDGES];
__device__ unsigned g_pairs[(size_t)NBUCK * BCAP];   // (loc<<24)|src
__device__ unsigned short g_xh[N_NODES * D];  // x in bf16
__device__ uint2 g_xq[N_NODES * 16];          // x in fp8 e4m3 (gather stream), row = 128B
__device__ unsigned short g_ah[N_NODES * D];  // a = mean-agg - x, in bf16
__device__ unsigned short g_wh[256 * D];      // [Ws;Wn], MFMA-fragment-ordered (see prep)

__device__ inline unsigned rne1(float f) {       // f32 -> bf16 bits, round-nearest-even
    unsigned b = __float_as_uint(f);
    return (b + 0x7FFFu + ((b >> 16) & 1u)) >> 16;
}
__device__ inline unsigned pack2(float a, float b) { return rne1(a) | (rne1(b) << 16); }
__device__ inline float bflo(unsigned u) { return __uint_as_float(u << 16); }
__device__ inline float bfhi(unsigned u) { return __uint_as_float(u & 0xFFFF0000u); }

// K1: blocks [0,6250): x -> g_xh (bf16) + g_xq (fp8)
//     blocks [6250,6378): W -> g_wh in MFMA-fragment order:
//       element (k,n): ct=n>>4, l15=n&15, kt=k>>5, lg=(k>>3)&3, j=k&7
//       idx = ((ct*8+kt)*64 + lg*16 + l15)*8 + j
//       -> a wave's B-frag load for (ct,kt) is 64 lanes x 16B CONTIGUOUS (1KB).
//     blocks [6378,6769): bin edges into per-bucket segments
__global__ __launch_bounds__(256) void prep_bin(const float* __restrict__ x,
                                                const float* __restrict__ Ws,
                                                const float* __restrict__ Wn,
                                                const int* __restrict__ ei)
{
    const int b = blockIdx.x;
    if (b < 6250) {
        const int i = b * 256 + threadIdx.x;       // uint4 chunk index (1.6M)
        const float4 f0 = reinterpret_cast<const float4*>(x)[i * 2 + 0];
        const float4 f1 = reinterpret_cast<const float4*>(x)[i * 2 + 1];
        uint4 o;
        o.x = pack2(f0.x, f0.y);
        o.y = pack2(f0.z, f0.w);
        o.z = pack2(f1.x, f1.y);
        o.w = pack2(f1.z, f1.w);
        reinterpret_cast<uint4*>(g_xh)[i] = o;
        int lo = __builtin_amdgcn_cvt_pk_fp8_f32(f0.x, f0.y, 0, false);
        lo = __builtin_amdgcn_cvt_pk_fp8_f32(f0.z, f0.w, lo, true);
        int hi = __builtin_amdgcn_cvt_pk_fp8_f32(f1.x, f1.y, 0, false);
        hi = __builtin_amdgcn_cvt_pk_fp8_f32(f1.z, f1.w, hi, true);
        g_xq[i] = make_uint2((unsigned)lo, (unsigned)hi);
    } else if (b < 6378) {
        const int tid = (b - 6250) * 256 + threadIdx.x;   // 32768
        const int k = tid >> 7, n = tid & 127;
        const float v = (k < 128) ? Ws[k * 128 + n] : Wn[(k - 128) * 128 + n];
        const int ct = n >> 4, l15 = n & 15;
        const int kt = k >> 5, lg = (k >> 3) & 3, j = k & 7;
        g_wh[((ct * 8 + kt) * 64 + lg * 16 + l15) * 8 + j] = (unsigned short)rne1(v);
    } else {
        __shared__ int cnt[NBUCK];
        __shared__ int cur[NBUCK];
        const int t = threadIdx.x;
        const int e0 = (b - 6378) * EPB;

        for (int k = t; k < NBUCK; k += 256) cnt[k] = 0;
        __syncthreads();

        int dstv[16], srcv[16];
        #pragma unroll
        for (int i = 0; i < 16; ++i) {
            const int e = e0 + i * 256 + t;
            if (e < N_EDGES) {
                dstv[i] = ei[N_EDGES + e];
                srcv[i] = ei[e];
                atomicAdd(&cnt[dstv[i] >> BSHIFT], 1);
            } else {
                dstv[i] = -1;
            }
        }
        __syncthreads();

        for (int k = t; k < NBUCK; k += 256) {
            const int c = cnt[k];
            cur[k] = (c > 0) ? atomicAdd(&g_bcur[k], c) : 0;
        }
        __syncthreads();

        #pragma unroll
        for (int i = 0; i < 16; ++i) {
            if (dstv[i] >= 0) {
                const int bk = dstv[i] >> BSHIFT;
                const int r = atomicAdd(&cur[bk], 1);
                g_pairs[(size_t)bk * BCAP + r] =
                    ((unsigned)(dstv[i] & (BNODES - 1)) << 24) | (unsigned)srcv[i];
            }
        }
    }
}

// K2: one block per bucket -> g_rowptr + g_csr (writes L2-confined).
__global__ __launch_bounds__(256) void bucket_build()
{
    __shared__ int red[256];
    __shared__ int lcnt[BNODES];
    __shared__ int lsum[BNODES];
    const int t = threadIdx.x;
    const int b = blockIdx.x;
    const int nE = g_bcur[b];
    const unsigned* __restrict__ seg = &g_pairs[(size_t)b * BCAP];

    int partial = 0;
    for (int i = t; i < b; i += 256) partial += g_bcur[i];
    red[t] = partial;
    lcnt[t] = 0;
    __syncthreads();
    for (int off = 128; off > 0; off >>= 1) {
        if (t < off) red[t] += red[t + off];
        __syncthreads();
    }
    const int base_edge = red[0];

    for (int i = t; i < nE; i += 256)
        atomicAdd(&lcnt[seg[i] >> 24], 1);
    __syncthreads();
    lsum[t] = lcnt[t];
    __syncthreads();
    for (int off = 1; off < 256; off <<= 1) {
        int add = (t >= off) ? lsum[t - off] : 0;
        __syncthreads();
        lsum[t] += add;
        __syncthreads();
    }
    const int excl = lsum[t] - lcnt[t];
    const int node = (b << BSHIFT) + t;
    if (node <= N_NODES) g_rowptr[node] = base_edge + excl;
    __syncthreads();
    lsum[t] = base_edge + excl;     // reuse as running cursor
    __syncthreads();
    for (int i = t; i < nE; i += 256) {
        const unsigned p = seg[i];
        const int pos = atomicAdd(&lsum[p >> 24], 1);
        g_csr[pos] = (int)(p & 0xFFFFFFu);
    }
}

// K3: pull-gather (fp8 stream): one NODE per 64-lane wave (100k waves, proven
// R10 structure). Quarter q handles rows base+4i+q; chunk c = lane&15 (8B).
__global__ __launch_bounds__(256) void sag_gather()
{
    const int gt = blockIdx.x * 256 + threadIdx.x;
    const int node = gt >> 6;
    const int q = (gt >> 4) & 3;
    const int c = gt & 15;
    const int beg = g_rowptr[node];
    const int end = g_rowptr[node + 1];
    const int deg = end - beg;

    float acc[8];
    #pragma unroll
    for (int i = 0; i < 8; ++i) acc[i] = 0.f;

    #define ACC8(v) do {                                                  \
        f32x2 p0 = __builtin_amdgcn_cvt_pk_f32_fp8((v).x, false);         \
        f32x2 p1 = __builtin_amdgcn_cvt_pk_f32_fp8((v).x, true);          \
        f32x2 p2 = __builtin_amdgcn_cvt_pk_f32_fp8((v).y, false);         \
        f32x2 p3 = __builtin_amdgcn_cvt_pk_f32_fp8((v).y, true);          \
        acc[0] += p0.x; acc[1] += p0.y; acc[2] += p1.x; acc[3] += p1.y;   \
        acc[4] += p2.x; acc[5] += p2.y; acc[6] += p3.x; acc[7] += p3.y;   \
    } while (0)

    int base = beg;
    for (; base + 16 <= end; base += 16) {
        const int s0 = g_csr[base + 0 + q];
        const int s1 = g_csr[base + 4 + q];
        const int s2 = g_csr[base + 8 + q];
        const int s3 = g_csr[base + 12 + q];
        const uint2 v0 = g_xq[s0 * 16 + c];
        const uint2 v1 = g_xq[s1 * 16 + c];
        const uint2 v2 = g_xq[s2 * 16 + c];
        const uint2 v3 = g_xq[s3 * 16 + c];
        ACC8(v0); ACC8(v1); ACC8(v2); ACC8(v3);
    }
    for (; base < end; base += 4) {
        if (base + q < end) {
            const int s = g_csr[base + q];
            const uint2 v = g_xq[s * 16 + c];
            ACC8(v);
        }
    }
    #undef ACC8

    #pragma unroll
    for (int i = 0; i < 8; ++i) {
        acc[i] += __shfl_xor(acc[i], 16, 64);
        acc[i] += __shfl_xor(acc[i], 32, 64);
    }

    if (q == 0) {
        uint4 res = make_uint4(0u, 0u, 0u, 0u);
        if (deg > 0) {
            const float inv = 1.f / (float)deg;
            const uint4 xv = reinterpret_cast<const uint4*>(g_xh)[node * 16 + c];
            float r0 = acc[0] * inv - bflo(xv.x), r1 = acc[1] * inv - bfhi(xv.x);
            float r2 = acc[2] * inv - bflo(xv.y), r3 = acc[3] * inv - bfhi(xv.y);
            float r4 = acc[4] * inv - bflo(xv.z), r5 = acc[5] * inv - bfhi(xv.z);
            float r6 = acc[6] * inv - bflo(xv.w), r7 = acc[7] * inv - bfhi(xv.w);
            res.x = pack2(r0, r1); res.y = pack2(r2, r3);
            res.z = pack2(r4, r5); res.w = pack2(r6, r7);
        }
        reinterpret_cast<uint4*>(g_ah)[node * 16 + c] = res;
    }
}

// K4: MFMA GEMM, NO LDS: out = [xh | ah] @ [Ws;Wn] + bias.
// B read per-fragment from fragment-ordered g_wh: one 1KB coalesced load per
// wave per (ct,kt), 64KB L2-resident W. No barriers, no LDS -> occupancy
// VGPR-limited (~3 waves/SIMD) instead of LDS-limited (2 blocks/CU).
// Block 0 re-zeroes g_bcur (dead after K2) for the next call.
__global__ __launch_bounds__(256) void sag_gemm_mfma(
    const float* __restrict__ bias,
    float* __restrict__ out)
{
    const int t = threadIdx.x;
    if (blockIdx.x == 0) {
        for (int i = t; i < NBUCK; i += 256) g_bcur[i] = 0;
    }

    const int w = t >> 6, l = t & 63;
    const int l15 = l & 15, lg = l >> 4;
    const int rbase = blockIdx.x * 128 + w * 32;

    const int r0 = min(rbase + l15, N_NODES - 1);
    const int r1 = min(rbase + 16 + l15, N_NODES - 1);
    const bf16x8* __restrict__ xh8 = reinterpret_cast<const bf16x8*>(g_xh);
    const bf16x8* __restrict__ ah8 = reinterpret_cast<const bf16x8*>(g_ah);
    bf16x8 a0[8], a1[8];
    #pragma unroll
    for (int kt = 0; kt < 4; ++kt) {
        a0[kt]     = xh8[r0 * 16 + kt * 4 + lg];
        a1[kt]     = xh8[r1 * 16 + kt * 4 + lg];
        a0[kt + 4] = ah8[r0 * 16 + kt * 4 + lg];
        a1[kt + 4] = ah8[r1 * 16 + kt * 4 + lg];
    }

    const bf16x8* __restrict__ wp = reinterpret_cast<const bf16x8*>(g_wh);  // frag order
    #pragma unroll
    for (int ct = 0; ct < 8; ++ct) {
        bf16x8 bfr[8];
        #pragma unroll
        for (int kt = 0; kt < 8; ++kt) bfr[kt] = wp[(ct * 8 + kt) * 64 + l];

        const int n = ct * 16 + l15;
        f32x4 acc0 = {0.f, 0.f, 0.f, 0.f};
        f32x4 acc1 = {0.f, 0.f, 0.f, 0.f};
        #pragma unroll
        for (int kt = 0; kt < 8; ++kt) {
            acc0 = __builtin_amdgcn_mfma_f32_16x16x32_bf16(a0[kt], bfr[kt], acc0, 0, 0, 0);
            acc1 = __builtin_amdgcn_mfma_f32_16x16x32_bf16(a1[kt], bfr[kt], acc1, 0, 0, 0);
        }
        const float bv = bias[n];
        #pragma unroll
        for (int i = 0; i < 4; ++i) {
            const int m0 = rbase + lg * 4 + i;          // D: row = 4*(l>>4)+i, col = l&15
            if (m0 < N_NODES)      out[m0 * D + n] = acc0[i] + bv;
            const int m1 = m0 + 16;
            if (m1 < N_NODES)      out[m1 * D + n] = acc1[i] + bv;
        }
    }
}

extern "C" void kernel_launch(void* const* d_in, const int* in_sizes, int n_in,
                              void* d_out, int out_size, void* d_ws, size_t ws_size,
                              hipStream_t stream) {
    const float* x     = (const float*)d_in[0];
    const int* ei      = (const int*)d_in[1];
    const float* Ws    = (const float*)d_in[2];
    const float* Wn    = (const float*)d_in[3];
    const float* bias  = (const float*)d_in[4];
    float* out = (float*)d_out;

    prep_bin<<<6769, 256, 0, stream>>>(x, Ws, Wn, ei);      // 6250 cvt + 128 W + 391 bin
    bucket_build<<<NBUCK, 256, 0, stream>>>();              // 391 blocks
    sag_gather<<<(N_NODES * 64) / 256, 256, 0, stream>>>();           // 25000 blocks
    sag_gemm_mfma<<<(N_NODES + 127) / 128, 256, 0, stream>>>(bias, out); // 782 blocks
}